// Round 8
// baseline (115.095 us; speedup 1.0000x reference)
//
#include <hip/hip_runtime.h>
#include <math.h>

#define K_ 32
#define D_ 8
#define NF 80          // 64 full-matrix quad + 8 lin + 1 const + 7 pad
#define NS 5           // NF/16 MFMA k-blocks
#define NTHREADS 256
#define NBLOCKS 1024
#define TPW 4          // tiles per wave, fully unrolled
#define REP 8          // DIAGNOSTIC: repeat compute 8x to surface gmm in top-5 counters

typedef _Float16 half8 __attribute__((ext_vector_type(8)));
typedef __fp16 fp16x2 __attribute__((ext_vector_type(2)));
typedef float f32x16 __attribute__((ext_vector_type(16)));

// ---------------------------------------------------------------------------
// Round-17: INSTRUMENTED MEASUREMENT. r15b kernel with the tile loop wrapped
// in REP=8; asm keep-live seals on xv per rep block cross-rep CSE (rule #17)
// so compute+store genuinely run 8x (loads 1x). This lifts the gmm dispatch
// to ~60us -> top-1 in rocprof, exposing VALUBusy/MfmaUtil/Occupancy/VGPR
// for the actual hot loop -- blind-spot since round 0.
// Evidence so far: warm gmm = 7.75us (r7 3x-launch); node gap <1us (r3 vs
// r4); 30% VALU cut had zero elasticity (r15) -> NOT VALU-issue-bound.
// This round decides between trans-bound / VGPR-occupancy-bound /
// stall-latency-bound. Math identical; outputs idempotent across reps.
// ---------------------------------------------------------------------------

__global__ void gmm_prep(
    const float* __restrict__ pi,
    const float* __restrict__ means,
    const float* __restrict__ chol,
    _Float16* __restrict__ wsV)
{
    const int k = threadIdx.x;
    if (k >= K_) return;

    // M starts as L (lower triangle), becomes Ci in-place, then A2 in-place.
    float M[D_][D_];
    {
        const float4* cp = (const float4*)(chol + k * 64);
#pragma unroll
        for (int i = 0; i < D_; ++i) {
            float4 a = cp[2 * i];
            M[i][0] = a.x; M[i][1] = a.y; M[i][2] = a.z; M[i][3] = a.w;
            if (i >= 4) {
                float4 bq = cp[2 * i + 1];
                M[i][4] = bq.x; M[i][5] = bq.y; M[i][6] = bq.z; M[i][7] = bq.w;
            }
        }
    }

    float rd[D_];
#pragma unroll
    for (int i = 0; i < D_; ++i) rd[i] = 1.f / M[i][i];

    float logdet = 0.f;
#pragma unroll
    for (int i = 0; i < D_; ++i) logdet += __logf(fabsf(rd[i]));
    logdet *= -2.f;

    // In-place TRTRI: column j overwritten with Ci[:,j].
#pragma unroll
    for (int j = 0; j < D_; ++j) {
        M[j][j] = rd[j];
#pragma unroll
        for (int i = j + 1; i < D_; ++i) {
            float s = 0.f;
#pragma unroll
            for (int mm = j; mm < i; ++mm) s += M[i][mm] * M[mm][j];
            M[i][j] = -s * rd[i];
        }
    }

    // In-place A2 = Ci^T Ci (lower): row i from temp (reads rows >= i only).
#pragma unroll
    for (int i = 0; i < D_; ++i) {
        float t[D_];
#pragma unroll
        for (int j = 0; j <= i; ++j) {
            float s = 0.f;
#pragma unroll
            for (int mm = i; mm < D_; ++mm) s += M[mm][i] * M[mm][j];
            t[j] = s;
        }
#pragma unroll
        for (int j = 0; j <= i; ++j) M[i][j] = t[j];
    }
    // M holds A2 lower triangle.

    float b[D_], q = 0.f;
    {
        const float4* mp = (const float4*)(means + k * 8);
        float4 ma = mp[0], mb = mp[1];
        float mu[D_] = {ma.x, ma.y, ma.z, ma.w, mb.x, mb.y, mb.z, mb.w};
#pragma unroll
        for (int i = 0; i < D_; ++i) {
            float s = 0.f;
#pragma unroll
            for (int j = 0; j <= i; ++j) s += M[i][j] * mu[j];
#pragma unroll
            for (int j = i + 1; j < D_; ++j) s += M[j][i] * mu[j];
            b[i] = s;
            q += s * mu[i];
        }
    }

    float lse;
    {
        float mx = pi[0];
#pragma unroll
        for (int t = 1; t < K_; ++t) mx = fmaxf(mx, pi[t]);
        float se = 0.f;
#pragma unroll
        for (int t = 0; t < K_; ++t) se += __expf(pi[t] - mx);
        lse = mx + __logf(se);
    }

    const float LOG2PI = 1.8378770664093453f;
    const float LOG2E  = 1.4426950408889634f;
    const float ALPHA  = 0.72134752044448170f;  // 0.5 * log2e
    float cst2 = ((pi[k] - lse) - 0.5f * (logdet + 8.f * LOG2PI)) * LOG2E;

    // Full-matrix V table: V[8i+j] = -alpha*A2[i][j] (UN-doubled, symmetric)
    float V[NF];
#pragma unroll
    for (int i = 0; i < D_; ++i)
#pragma unroll
        for (int j = 0; j < D_; ++j)
            V[8 * i + j] = -ALPHA * ((i >= j) ? M[i][j] : M[j][i]);
#pragma unroll
    for (int j = 0; j < D_; ++j) V[64 + j] = 2.f * ALPHA * b[j];
    V[72] = cst2 - ALPHA * q;
#pragma unroll
    for (int j = 73; j < NF; ++j) V[j] = 0.f;

    // fragment table: hot-kernel lane l reads wsV[s][l][0..7], l = h*32 + k
#pragma unroll
    for (int s = 0; s < NS; ++s)
#pragma unroll
        for (int h = 0; h < 2; ++h) {
            half8 hv;
#pragma unroll
            for (int j = 0; j < 8; ++j) hv[j] = (_Float16)V[16 * s + 8 * h + j];
            *(half8*)&wsV[(s * 64 + h * 32 + k) * 8] = hv;
        }
}

__global__ __launch_bounds__(NTHREADS) void gmm_mfma(
    const float* __restrict__ x,
    const _Float16* __restrict__ wsV,
    float* __restrict__ out)
{
    const int tid  = threadIdx.x;
    const int lane = tid & 63;
    const int m    = lane & 31;
    const bool h1  = lane >= 32;

    const int w  = blockIdx.x * (NTHREADS / 64) + (tid >> 6);
    const int t0 = w * TPW;
    const float4* xp = (const float4*)x;
    const float LN2 = 0.69314718055994531f;

    // ---- all x-loads issued first (once; reps reuse registers) ----
    float xv[TPW][D_];
#pragma unroll
    for (int u = 0; u < TPW; ++u) {
        const int n = (t0 + u) * 32 + m;
        float4 a = xp[2 * n], b2 = xp[2 * n + 1];
        xv[u][0] = a.x;  xv[u][1] = a.y;  xv[u][2] = a.z;  xv[u][3] = a.w;
        xv[u][4] = b2.x; xv[u][5] = b2.y; xv[u][6] = b2.z; xv[u][7] = b2.w;
    }

    // A-fragments from the 5KB L2-resident table
    const half8* wp = (const half8*)wsV;
    half8 wf[NS];
#pragma unroll
    for (int s = 0; s < NS; ++s) wf[s] = wp[s * 64 + lane];

    // loop-invariant constants: zero C-operand, (1,0,...,0) const fragment
    f32x16 zc;
#pragma unroll
    for (int r = 0; r < 16; ++r) zc[r] = 0.f;
    half8 c10;
#pragma unroll
    for (int j = 0; j < 8; ++j) c10[j] = (_Float16)((j == 0) ? 1.f : 0.f);

    for (int rep = 0; rep < REP; ++rep) {
        // seal xv per rep: blocks cross-rep CSE, keeps compute honest (rule #17)
#pragma unroll
        for (int u = 0; u < TPW; ++u)
#pragma unroll
            for (int i = 0; i < D_; ++i)
                asm volatile("" : "+v"(xv[u][i]));

#pragma unroll
        for (int u = 0; u < TPW; ++u) {
            // row-structured fragments: slice (s,h) = row i=2s+h of x_i*x_j.
            half8 bq[4];
#pragma unroll
            for (int s = 0; s < 4; ++s) {
                float bc = h1 ? xv[u][2 * s + 1] : xv[u][2 * s];
#pragma unroll
                for (int jp = 0; jp < 4; ++jp) {
                    fp16x2 pk = __builtin_amdgcn_cvt_pkrtz(bc * xv[u][2 * jp],
                                                           bc * xv[u][2 * jp + 1]);
                    bq[s][2 * jp]     = (_Float16)pk[0];
                    bq[s][2 * jp + 1] = (_Float16)pk[1];
                }
            }
            // s=4 block: h0 = linear features (packed x), h1 = (1,0,...)
            half8 xh;
#pragma unroll
            for (int jp = 0; jp < 4; ++jp) {
                fp16x2 pk = __builtin_amdgcn_cvt_pkrtz(xv[u][2 * jp], xv[u][2 * jp + 1]);
                xh[2 * jp]     = (_Float16)pk[0];
                xh[2 * jp + 1] = (_Float16)pk[1];
            }
            half8 bf4 = h1 ? c10 : xh;

            f32x16 acc;
            acc = __builtin_amdgcn_mfma_f32_32x32x16_f16(wf[0], bq[0], zc,  0, 0, 0);
            acc = __builtin_amdgcn_mfma_f32_32x32x16_f16(wf[1], bq[1], acc, 0, 0, 0);
            acc = __builtin_amdgcn_mfma_f32_32x32x16_f16(wf[2], bq[2], acc, 0, 0, 0);
            acc = __builtin_amdgcn_mfma_f32_32x32x16_f16(wf[3], bq[3], acc, 0, 0, 0);
            acc = __builtin_amdgcn_mfma_f32_32x32x16_f16(wf[4], bf4,   acc, 0, 0, 0);

            // k-reduce: 16 exp2 + pairwise tree + cross-half shfl
            float e0 = exp2f(acc[0]),  e1 = exp2f(acc[1]),  e2 = exp2f(acc[2]),  e3 = exp2f(acc[3]);
            float e4 = exp2f(acc[4]),  e5 = exp2f(acc[5]),  e6 = exp2f(acc[6]),  e7 = exp2f(acc[7]);
            float e8 = exp2f(acc[8]),  e9 = exp2f(acc[9]),  ea = exp2f(acc[10]), eb = exp2f(acc[11]);
            float ec = exp2f(acc[12]), ed = exp2f(acc[13]), ee = exp2f(acc[14]), ef = exp2f(acc[15]);
            float s0 = (e0 + e1) + (e2 + e3);
            float s1 = (e4 + e5) + (e6 + e7);
            float s2 = (e8 + e9) + (ea + eb);
            float s3 = (ec + ed) + (ee + ef);
            float tot = (s0 + s1) + (s2 + s3);
            tot += __shfl_xor(tot, 32, 64);
            float res = log2f(tot) * LN2;
            if (!h1) out[(t0 + u) * 32 + m] = res;  // idempotent across reps
        }
    }
}

extern "C" void kernel_launch(void* const* d_in, const int* in_sizes, int n_in,
                              void* d_out, int out_size, void* d_ws, size_t ws_size,
                              hipStream_t stream) {
    const float* x     = (const float*)d_in[0];
    const float* pi    = (const float*)d_in[1];
    const float* means = (const float*)d_in[2];
    const float* chol  = (const float*)d_in[3];
    float* out = (float*)d_out;
    _Float16* wsV = (_Float16*)d_ws;
    (void)in_sizes; (void)n_in; (void)out_size; (void)ws_size;

    gmm_prep<<<1, 64, 0, stream>>>(pi, means, chol, wsV);
    gmm_mfma<<<NBLOCKS, NTHREADS, 0, stream>>>(x, wsV, out);
}

// Round 9
// 74.191 us; speedup vs baseline: 1.5513x; 1.5513x over previous
//
#include <hip/hip_runtime.h>
#include <math.h>

#define K_ 32
#define D_ 8
#define NF 80          // 64 full-matrix quad + 8 lin + 1 const + 7 pad
#define NS 5           // NF/16 MFMA k-blocks
#define NTHREADS 256
#define NBLOCKS 2048   // r18: 8192 waves = 8 waves/SIMD (trans-latency hiding)
#define TPW 2          // r18: tiles per wave halved; same total tiles

typedef _Float16 half8 __attribute__((ext_vector_type(8)));
typedef __fp16 fp16x2 __attribute__((ext_vector_type(2)));
typedef float f32x2 __attribute__((ext_vector_type(2)));
typedef float f32x16 __attribute__((ext_vector_type(16)));

// ---------------------------------------------------------------------------
// Round-18: cut VALU issue cycles + fill issue gaps.
// r17 instrumented counters (REP=8): VALUBusy 81.6%, MfmaUtil 14.6%, VGPR=52,
// 0 LDS conflicts -> hot loop IS VALU-issue-bound. Measured issue cycles
// (82% x 6.9us) match the static instruction count at ~800 MHz core clock:
// the kernel runs in a DVFS valley behind the 6.3 TB/s fills. Clock is not
// controllable; cycles are. Two levers:
//  1. packed-f32 (VOP3P): build muls and exp-sum tree written as float2
//     arithmetic -> v_pk_mul_f32 / v_pk_add_f32 (gfx950). 32 mul -> 16 pk,
//     15 add -> 7 pk + 1. IEEE-identical numerics; falls back to scalar
//     harmlessly if the backend declines.
//  2. TLP: TPW 4->2, NBLOCKS 1024->2048 = 8 waves/SIMD (was 4) to fill the
//     18% idle issue slots during 16-deep quarter-rate v_exp_f32 bursts.
// Decision rule (pre-committed): dur >= 74 -> cycle-elasticity exhausted at
// this scale; remaining dur = ~61us harness fixed + ~5-6us near-floor kernel
// -> ROOFLINE next round.
//
// Math (unchanged): W2[n][k] = sum_f V[k][f] Y[n][f];
//   Y = [x_i x_j (all i,j), x, 1, pad]; V[8i+j] = -alpha*A2[i][j];
//   out = ln2 * log2(sum_k exp2(W2))   (W2 in (-80,-3), no max-subtract)
// C-layout (32x32x16): row=k=(reg&3)+8*(reg>>2)+4*(lane>>5), col=lane&31.
// Grid: 2048 blk x 4 waves x 2 tiles = 16384 tiles = N/32.
// ---------------------------------------------------------------------------

__global__ void gmm_prep(
    const float* __restrict__ pi,
    const float* __restrict__ means,
    const float* __restrict__ chol,
    _Float16* __restrict__ wsV)
{
    const int k = threadIdx.x;
    if (k >= K_) return;

    // M starts as L (lower triangle), becomes Ci in-place, then A2 in-place.
    float M[D_][D_];
    {
        const float4* cp = (const float4*)(chol + k * 64);
#pragma unroll
        for (int i = 0; i < D_; ++i) {
            float4 a = cp[2 * i];
            M[i][0] = a.x; M[i][1] = a.y; M[i][2] = a.z; M[i][3] = a.w;
            if (i >= 4) {
                float4 bq = cp[2 * i + 1];
                M[i][4] = bq.x; M[i][5] = bq.y; M[i][6] = bq.z; M[i][7] = bq.w;
            }
        }
    }

    float rd[D_];
#pragma unroll
    for (int i = 0; i < D_; ++i) rd[i] = 1.f / M[i][i];

    float logdet = 0.f;
#pragma unroll
    for (int i = 0; i < D_; ++i) logdet += __logf(fabsf(rd[i]));
    logdet *= -2.f;

    // In-place TRTRI: column j overwritten with Ci[:,j].
#pragma unroll
    for (int j = 0; j < D_; ++j) {
        M[j][j] = rd[j];
#pragma unroll
        for (int i = j + 1; i < D_; ++i) {
            float s = 0.f;
#pragma unroll
            for (int mm = j; mm < i; ++mm) s += M[i][mm] * M[mm][j];
            M[i][j] = -s * rd[i];
        }
    }

    // In-place A2 = Ci^T Ci (lower): row i from temp (reads rows >= i only).
#pragma unroll
    for (int i = 0; i < D_; ++i) {
        float t[D_];
#pragma unroll
        for (int j = 0; j <= i; ++j) {
            float s = 0.f;
#pragma unroll
            for (int mm = i; mm < D_; ++mm) s += M[mm][i] * M[mm][j];
            t[j] = s;
        }
#pragma unroll
        for (int j = 0; j <= i; ++j) M[i][j] = t[j];
    }
    // M holds A2 lower triangle.

    float b[D_], q = 0.f;
    {
        const float4* mp = (const float4*)(means + k * 8);
        float4 ma = mp[0], mb = mp[1];
        float mu[D_] = {ma.x, ma.y, ma.z, ma.w, mb.x, mb.y, mb.z, mb.w};
#pragma unroll
        for (int i = 0; i < D_; ++i) {
            float s = 0.f;
#pragma unroll
            for (int j = 0; j <= i; ++j) s += M[i][j] * mu[j];
#pragma unroll
            for (int j = i + 1; j < D_; ++j) s += M[j][i] * mu[j];
            b[i] = s;
            q += s * mu[i];
        }
    }

    float lse;
    {
        float mx = pi[0];
#pragma unroll
        for (int t = 1; t < K_; ++t) mx = fmaxf(mx, pi[t]);
        float se = 0.f;
#pragma unroll
        for (int t = 0; t < K_; ++t) se += __expf(pi[t] - mx);
        lse = mx + __logf(se);
    }

    const float LOG2PI = 1.8378770664093453f;
    const float LOG2E  = 1.4426950408889634f;
    const float ALPHA  = 0.72134752044448170f;  // 0.5 * log2e
    float cst2 = ((pi[k] - lse) - 0.5f * (logdet + 8.f * LOG2PI)) * LOG2E;

    // Full-matrix V table: V[8i+j] = -alpha*A2[i][j] (UN-doubled, symmetric)
    float V[NF];
#pragma unroll
    for (int i = 0; i < D_; ++i)
#pragma unroll
        for (int j = 0; j < D_; ++j)
            V[8 * i + j] = -ALPHA * ((i >= j) ? M[i][j] : M[j][i]);
#pragma unroll
    for (int j = 0; j < D_; ++j) V[64 + j] = 2.f * ALPHA * b[j];
    V[72] = cst2 - ALPHA * q;
#pragma unroll
    for (int j = 73; j < NF; ++j) V[j] = 0.f;

    // fragment table: hot-kernel lane l reads wsV[s][l][0..7], l = h*32 + k
#pragma unroll
    for (int s = 0; s < NS; ++s)
#pragma unroll
        for (int h = 0; h < 2; ++h) {
            half8 hv;
#pragma unroll
            for (int j = 0; j < 8; ++j) hv[j] = (_Float16)V[16 * s + 8 * h + j];
            *(half8*)&wsV[(s * 64 + h * 32 + k) * 8] = hv;
        }
}

__global__ __launch_bounds__(NTHREADS) void gmm_mfma(
    const float* __restrict__ x,
    const _Float16* __restrict__ wsV,
    float* __restrict__ out)
{
    const int tid  = threadIdx.x;
    const int lane = tid & 63;
    const int m    = lane & 31;
    const bool h1  = lane >= 32;

    const int w  = blockIdx.x * (NTHREADS / 64) + (tid >> 6);
    const int t0 = w * TPW;
    const float4* xp = (const float4*)x;
    const float LN2 = 0.69314718055994531f;

    // ---- all x-loads issued first; xv held as float2 pairs (pk-f32 feed) ----
    f32x2 xv[TPW][4];
#pragma unroll
    for (int u = 0; u < TPW; ++u) {
        const int n = (t0 + u) * 32 + m;
        float4 a = xp[2 * n], b2 = xp[2 * n + 1];
        xv[u][0] = (f32x2){a.x,  a.y};
        xv[u][1] = (f32x2){a.z,  a.w};
        xv[u][2] = (f32x2){b2.x, b2.y};
        xv[u][3] = (f32x2){b2.z, b2.w};
    }

    // A-fragments from the 5KB L2-resident table
    const half8* wp = (const half8*)wsV;
    half8 wf[NS];
#pragma unroll
    for (int s = 0; s < NS; ++s) wf[s] = wp[s * 64 + lane];

    // loop-invariant constants: zero C-operand, (1,0,...,0) const fragment
    f32x16 zc;
#pragma unroll
    for (int r = 0; r < 16; ++r) zc[r] = 0.f;
    half8 c10;
#pragma unroll
    for (int j = 0; j < 8; ++j) c10[j] = (_Float16)((j == 0) ? 1.f : 0.f);

#pragma unroll
    for (int u = 0; u < TPW; ++u) {
        // row-structured fragments: slice (s,h) = row i=2s+h of x_i*x_j.
        // bc = x_{2s+h}; products via v_pk_mul_f32 (float2), packed by pkrtz.
        half8 bq[4];
#pragma unroll
        for (int s = 0; s < 4; ++s) {
            float bc = h1 ? xv[u][s].y : xv[u][s].x;
            f32x2 bc2 = (f32x2){bc, bc};
#pragma unroll
            for (int jp = 0; jp < 4; ++jp) {
                f32x2 pr = bc2 * xv[u][jp];           // v_pk_mul_f32
                fp16x2 pk = __builtin_amdgcn_cvt_pkrtz(pr.x, pr.y);
                bq[s][2 * jp]     = (_Float16)pk[0];
                bq[s][2 * jp + 1] = (_Float16)pk[1];
            }
        }
        // s=4 block: h0 = linear features (packed x), h1 = (1,0,...)
        half8 xh;
#pragma unroll
        for (int jp = 0; jp < 4; ++jp) {
            fp16x2 pk = __builtin_amdgcn_cvt_pkrtz(xv[u][jp].x, xv[u][jp].y);
            xh[2 * jp]     = (_Float16)pk[0];
            xh[2 * jp + 1] = (_Float16)pk[1];
        }
        half8 bf4 = h1 ? c10 : xh;

        f32x16 acc;
        acc = __builtin_amdgcn_mfma_f32_32x32x16_f16(wf[0], bq[0], zc,  0, 0, 0);
        acc = __builtin_amdgcn_mfma_f32_32x32x16_f16(wf[1], bq[1], acc, 0, 0, 0);
        acc = __builtin_amdgcn_mfma_f32_32x32x16_f16(wf[2], bq[2], acc, 0, 0, 0);
        acc = __builtin_amdgcn_mfma_f32_32x32x16_f16(wf[3], bq[3], acc, 0, 0, 0);
        acc = __builtin_amdgcn_mfma_f32_32x32x16_f16(wf[4], bf4,   acc, 0, 0, 0);

        // k-reduce: 16 exp2 + packed pairwise tree (v_pk_add_f32) + shfl
        f32x2 v0 = (f32x2){exp2f(acc[0]),  exp2f(acc[1])};
        f32x2 v1 = (f32x2){exp2f(acc[2]),  exp2f(acc[3])};
        f32x2 v2 = (f32x2){exp2f(acc[4]),  exp2f(acc[5])};
        f32x2 v3 = (f32x2){exp2f(acc[6]),  exp2f(acc[7])};
        f32x2 v4 = (f32x2){exp2f(acc[8]),  exp2f(acc[9])};
        f32x2 v5 = (f32x2){exp2f(acc[10]), exp2f(acc[11])};
        f32x2 v6 = (f32x2){exp2f(acc[12]), exp2f(acc[13])};
        f32x2 v7 = (f32x2){exp2f(acc[14]), exp2f(acc[15])};
        f32x2 w0 = v0 + v1, w1 = v2 + v3, w2 = v4 + v5, w3 = v6 + v7;
        f32x2 u0 = w0 + w1, u1 = w2 + w3;
        f32x2 z  = u0 + u1;
        float tot = z.x + z.y;
        tot += __shfl_xor(tot, 32, 64);
        float res = log2f(tot) * LN2;
        if (!h1) out[(t0 + u) * 32 + m] = res;  // coalesced 128B store
    }
}

extern "C" void kernel_launch(void* const* d_in, const int* in_sizes, int n_in,
                              void* d_out, int out_size, void* d_ws, size_t ws_size,
                              hipStream_t stream) {
    const float* x     = (const float*)d_in[0];
    const float* pi    = (const float*)d_in[1];
    const float* means = (const float*)d_in[2];
    const float* chol  = (const float*)d_in[3];
    float* out = (float*)d_out;
    _Float16* wsV = (_Float16*)d_ws;
    (void)in_sizes; (void)n_in; (void)out_size; (void)ws_size;

    gmm_prep<<<1, 64, 0, stream>>>(pi, means, chol, wsV);
    gmm_mfma<<<NBLOCKS, NTHREADS, 0, stream>>>(x, wsV, out);
}